// Round 5
// baseline (277.674 us; speedup 1.0000x reference)
//
#include <hip/hip_runtime.h>
#include <math.h>

// Problem constants
#define NB 32
#define NC 64          // CODE_DIM
#define NK 2048
#define NCODES 1024
#define NVEC (NB*NK)          // 65536 vectors
#define NELEM (NB*NC*NK)      // 4194304 elements
#define NBLK 1024             // 64 vectors per block (256B row writes!)

#define MARGIN 1.5e-3f        // rigorous bf16-proxy bound (validated R5)
#define CAP 32

// ws layout (bytes)
#define WS_HIST  0            // int[1024]      = 4096
#define WS_CBN32 4096         // float[1024]    = 4096
#define WS_PART  8192         // double[1024]   = 8192
#define WS_CTR   24576        // unsigned int   = 4
#define WS_CBBF  32768        // __bf16[65536]  = 131072

typedef __bf16 bf16x8 __attribute__((ext_vector_type(8)));
typedef float  f32x4  __attribute__((ext_vector_type(4)));
#define MFMA16(A, B, ACC) __builtin_amdgcn_mfma_f32_16x16x32_bf16(A, B, ACC, 0, 0, 0)

// --- codebook prep: numpy-exact fp32 norms (same summation order as validated
// version -> bit-identical n32) + bf16 copy; block 0 zeroes hist + ctr. ------
__global__ void k_cbprep(const float* __restrict__ cb, float* __restrict__ n32,
                         __bf16* __restrict__ cbbf, int* __restrict__ hist,
                         unsigned int* __restrict__ ctr) {
    const int t = threadIdx.x;
    const int j = blockIdx.x * 64 + t;   // 16 x 64 = 1024
    if (blockIdx.x == 0) {
        int4 z4; z4.x = 0; z4.y = 0; z4.z = 0; z4.w = 0;
#pragma unroll
        for (int i = 0; i < 4; i++) ((int4*)hist)[t * 4 + i] = z4;
        if (t == 0) *ctr = 0u;
    }
    const float* cr = cb + (size_t)j * NC;
    float x[64];
#pragma unroll
    for (int i = 0; i < 16; i++) {
        f32x4 tv = *(const f32x4*)(cr + 4 * i);
        x[4*i+0] = tv[0]; x[4*i+1] = tv[1]; x[4*i+2] = tv[2]; x[4*i+3] = tv[3];
    }
    // EXACT same chain as validated version (order preserved)
    float r[8];
#pragma unroll
    for (int q = 0; q < 8; q++) r[q] = __fmul_rn(x[q], x[q]);
#pragma unroll
    for (int i = 8; i < 64; i += 8)
#pragma unroll
        for (int q = 0; q < 8; q++)
            r[q] = __fadd_rn(r[q], __fmul_rn(x[i + q], x[i + q]));
    float s01 = __fadd_rn(r[0], r[1]), s23 = __fadd_rn(r[2], r[3]);
    float s45 = __fadd_rn(r[4], r[5]), s67 = __fadd_rn(r[6], r[7]);
    n32[j] = __fadd_rn(__fadd_rn(s01, s23), __fadd_rn(s45, s67));
    __bf16* br = cbbf + (size_t)j * NC;
#pragma unroll
    for (int i = 0; i < 8; i++) {
        bf16x8 o;
#pragma unroll
        for (int q = 0; q < 8; q++) o[q] = (__bf16)x[8*i + q];
        *(bf16x8*)(br + 8*i) = o;
    }
}

// --- fused VQ: 8-wave blocks, R2 memory shape --------------------------------
// Block: 512 thr = 8 waves; 64 vectors (k-extent 64 floats = 256B row writes,
// the R4 lesson: never fragment below sector granularity). Grid 1024 blocks ->
// 8192 waves = 8 waves/SIMD (HW max TLP), 4 blocks/CU (VGPR<=64 via
// __launch_bounds__(512,8); R2 measured 56 with this live set). Wave w owns
// codes [w*128,(w+1)*128) = 8 tiles, B-frags streamed from L2. pd =
// fma(-2,acc,nvv) == sub(nvv,mul(2,acc)) bit-exact (validated R4). t1 computed
// ONCE per vector by wave 0 (identical chain -> bit-identical), broadcast via
// LDS, overlapped with other waves' pass-2. cand/keys2/wmin minor strides
// padded to kill 32-way bank aliases. Last-block finalize replicates the
// validated k_final reduction exactly.
// MFMA 16x16x32 bf16 layout (validated R5): A[m=lane&15][k=quad*8+j];
// B[n=lane&15][k=quad*8+j]; D col=lane&15 (code), row=quad*4+reg (vector).
__launch_bounds__(512, 8)
__global__ void k_vq(const float* __restrict__ ze, const float* __restrict__ cb,
                     const float* __restrict__ n32, const __bf16* __restrict__ cbbf,
                     int* __restrict__ hist, float* __restrict__ codes_f,
                     float* __restrict__ outq, double* __restrict__ part,
                     unsigned int* __restrict__ ctr, float* __restrict__ outsc) {
    __shared__ float wmin[64][9];            // padded (bank spread)
    __shared__ float gthr[64];
    __shared__ float t1s[64];
    __shared__ int cnt[64];
    __shared__ int cand[64][CAP + 1];        // padded (bank spread)
    __shared__ unsigned long long keys2[64][9];  // padded
    __shared__ int codearr[64];
    __shared__ double lsd[8];
    __shared__ int lastflag;
    __shared__ double TL[16], TE[16];

    const int t = threadIdx.x;
    const int L = t & 63;
    const int w = t >> 6;            // wave 0..7
    const int quad = L >> 4;
    const int col = L & 15;
    const int vec0 = blockIdx.x * 64;
    const int b = vec0 >> 11;
    const int k0 = vec0 & (NK - 1);
    const float* zbase = ze + (size_t)b * NC * NK + k0;

    // ---- A-frags for all 64 vectors (reg-resident, 32 VGPR) ----------------
    bf16x8 af[4][2];
#pragma unroll
    for (int vt = 0; vt < 4; vt++)
#pragma unroll
        for (int kt = 0; kt < 2; kt++)
#pragma unroll
            for (int j = 0; j < 8; j++)
                af[vt][kt][j] =
                    (__bf16)zbase[(size_t)(kt*32 + quad*8 + j) * NK + vt*16 + col];

    // ---- pass 1: per-lane proxy min over wave's 128 codes ------------------
    float pmin[4][4];
#pragma unroll
    for (int vt = 0; vt < 4; vt++)
#pragma unroll
        for (int r = 0; r < 4; r++) pmin[vt][r] = 1e30f;
#pragma unroll 2
    for (int tile = 0; tile < 8; tile++) {   // unroll 2: cap live B-regs
        const __bf16* brow = cbbf + (size_t)(w*128 + tile*16 + col) * NC + quad*8;
        bf16x8 b0 = *(const bf16x8*)(brow);
        bf16x8 b1 = *(const bf16x8*)(brow + 32);
        float nvv = n32[w*128 + tile*16 + col];
#pragma unroll
        for (int vt = 0; vt < 4; vt++) {   // 4 independent MFMA chains (ILP)
            f32x4 acc = {0.f, 0.f, 0.f, 0.f};
            acc = MFMA16(af[vt][0], b0, acc);
            acc = MFMA16(af[vt][1], b1, acc);
#pragma unroll
            for (int r = 0; r < 4; r++) {
                float pd = __fmaf_rn(-2.f, acc[r], nvv);  // == sub(nvv,mul(2,acc))
                pmin[vt][r] = fminf(pmin[vt][r], pd);
            }
        }
    }
    // one-time cross-col reduce
#pragma unroll
    for (int vt = 0; vt < 4; vt++)
#pragma unroll
        for (int r = 0; r < 4; r++) {
            float pm = pmin[vt][r];
            pm = fminf(pm, __shfl_xor(pm, 1, 16));
            pm = fminf(pm, __shfl_xor(pm, 2, 16));
            pm = fminf(pm, __shfl_xor(pm, 4, 16));
            pm = fminf(pm, __shfl_xor(pm, 8, 16));
            if (col == 0) wmin[vt*16 + quad*4 + r][w] = pm;
        }
    __syncthreads();

    if (t < 64) {
        float g = wmin[t][0];
#pragma unroll
        for (int ww = 1; ww < 8; ww++) g = fminf(g, wmin[t][ww]);
        gthr[t] = g + MARGIN;
        cnt[t] = 0;
    }
    __syncthreads();

    // ---- wave 0: exact t1 per vector (validated chain, computed once) ------
    // Other waves proceed straight into pass 2; t1s is consumed only after the
    // next __syncthreads(), so no extra barrier is needed.
    if (t < 64) {
        const int v = t;
        float rr[8];
#pragma unroll
        for (int q = 0; q < 8; q++) {
            float xx = zbase[(size_t)q * NK + v];
            rr[q] = __fmul_rn(xx, xx);
        }
#pragma unroll
        for (int i = 8; i < 64; i += 8)
#pragma unroll
            for (int q = 0; q < 8; q++) {
                float xx = zbase[(size_t)(i + q) * NK + v];
                rr[q] = __fadd_rn(rr[q], __fmul_rn(xx, xx));
            }
        float s01 = __fadd_rn(rr[0], rr[1]), s23 = __fadd_rn(rr[2], rr[3]);
        float s45 = __fadd_rn(rr[4], rr[5]), s67 = __fadd_rn(rr[6], rr[7]);
        t1s[v] = __fadd_rn(__fadd_rn(s01, s23), __fadd_rn(s45, s67));
    }

    // ---- pass 2: capture candidates within MARGIN of global proxy min ------
    float thr[4][4];
#pragma unroll
    for (int vt = 0; vt < 4; vt++)
#pragma unroll
        for (int r = 0; r < 4; r++) thr[vt][r] = gthr[vt*16 + quad*4 + r];
#pragma unroll 2
    for (int tile = 0; tile < 8; tile++) {
        const __bf16* brow = cbbf + (size_t)(w*128 + tile*16 + col) * NC + quad*8;
        bf16x8 b0 = *(const bf16x8*)(brow);
        bf16x8 b1 = *(const bf16x8*)(brow + 32);
        float nvv = n32[w*128 + tile*16 + col];
#pragma unroll
        for (int vt = 0; vt < 4; vt++) {
            f32x4 acc = {0.f, 0.f, 0.f, 0.f};
            acc = MFMA16(af[vt][0], b0, acc);
            acc = MFMA16(af[vt][1], b1, acc);
#pragma unroll
            for (int r = 0; r < 4; r++) {
                float pd = __fmaf_rn(-2.f, acc[r], nvv);
                if (pd <= thr[vt][r]) {
                    int m = vt*16 + quad*4 + r;
                    int slot = atomicAdd(&cnt[m], 1);
                    if (slot < CAP) cand[m][slot] = w*128 + tile*16 + col;
                }
            }
        }
    }
    __syncthreads();

    // ---- exact rescore: 8 threads/vector, validated bit-exact fp32 chain ---
    {
        const int v = L;               // vector; this thread handles part w
        const float t1 = t1s[v];
        int cc = cnt[v];
        unsigned long long kmin = 0xFFFFFFFFFFFFFFFFULL;
        if (cc <= CAP) {
            for (int si = w; si < cc; si += 8) {
                int j = cand[v][si];
                const float* cr = cb + (size_t)j * NC;
                float a = 0.f;
#pragma unroll
                for (int c = 0; c < NC; c++)
                    a = __fmaf_rn(zbase[(size_t)c * NK + v], cr[c], a);
                float d = __fmaf_rn(-2.f, a, __fadd_rn(t1, n32[j]));
                unsigned long long key =
                    ((unsigned long long)__float_as_uint(d) << 32) | (unsigned int)j;
                if (key < kmin) kmin = key;
            }
        } else {   // overflow fallback: exact full scan split over 8 waves
            for (int j = w * 128; j < (w + 1) * 128; j++) {
                const float* cr = cb + (size_t)j * NC;
                float a = 0.f;
#pragma unroll
                for (int c = 0; c < NC; c++)
                    a = __fmaf_rn(zbase[(size_t)c * NK + v], cr[c], a);
                float d = __fmaf_rn(-2.f, a, __fadd_rn(t1, n32[j]));
                unsigned long long key =
                    ((unsigned long long)__float_as_uint(d) << 32) | (unsigned int)j;
                if (key < kmin) kmin = key;
            }
        }
        keys2[v][w] = kmin;
    }
    __syncthreads();

    if (t < 64) {   // merge 8 partial keys: min dist, ties -> min idx (np rule)
        unsigned long long kmin = keys2[t][0];
#pragma unroll
        for (int ww = 1; ww < 8; ww++) {
            unsigned long long kk = keys2[t][ww];
            if (kk < kmin) kmin = kk;
        }
        int code = (int)(kmin & 0xFFFFFFFFu);
        codearr[t] = code;
        codes_f[vec0 + t] = (float)code;
        atomicAdd(&hist[code], 1);
    }
    __syncthreads();

    // ---- quant epilogue: float4; per c-row 16 thr x 16B = 256B contiguous --
    double s = 0.0;
    float* ob = outq + (size_t)b * NC * NK + k0;
    const int c0 = t >> 4;             // 0..31
    const int v0 = (t & 15) * 4;       // 0,4,..,60
    int cds[4];
#pragma unroll
    for (int u = 0; u < 4; u++) cds[u] = codearr[v0 + u];
#pragma unroll
    for (int half = 0; half < 2; half++) {
        const int c = c0 + half * 32;
        f32x4 zv = *(const f32x4*)(zbase + (size_t)c * NK + v0);
        f32x4 ov;
#pragma unroll
        for (int u = 0; u < 4; u++) {
            float qv = cb[(size_t)cds[u] * NC + c];
            ov[u] = __fadd_rn(zv[u], __fsub_rn(qv, zv[u]));
            double d = (double)qv - (double)zv[u];
            s += d * d;
        }
        *(f32x4*)(ob + (size_t)c * NK + v0) = ov;
    }
    for (int off = 32; off; off >>= 1) s += __shfl_down(s, off);
    if (L == 0) lsd[w] = s;
    __syncthreads();
    if (t == 0) {
        double tot = 0.0;
#pragma unroll
        for (int i = 0; i < 8; i++) tot += lsd[i];
        part[blockIdx.x] = tot;
        __threadfence();                             // part+hist visible first
        unsigned int my = atomicAdd(ctr, 1u);
        lastflag = (my == NBLK - 1) ? 1 : 0;
    }
    __syncthreads();

    // ---- last block: finalize (exact replica of old k_final reduction) -----
    if (lastflag) {
        __threadfence();   // acquire side
        // 16 groups of 64 partials; wave w handles groups w and w+8 (same
        // shfl_down tree as validated k_final; t0 sums groups 0..15 in order)
#pragma unroll
        for (int gi = 0; gi < 2; gi++) {
            int g = w + gi * 8;
            double vL = part[g * 64 + L];
            for (int off = 32; off; off >>= 1) vL += __shfl_down(vL, off);
            if (L == 0) TL[g] = vL;
        }
#pragma unroll
        for (int gi = 0; gi < 2; gi++) {
            int g = w + gi * 8;
            double pp = (double)hist[g * 64 + L] * (1.0 / (double)NVEC);
            double vE = pp * log(pp + 1e-10);
            for (int off = 32; off; off >>= 1) vE += __shfl_down(vE, off);
            if (L == 0) TE[g] = vE;
        }
        __syncthreads();
        if (t == 0) {
            double SL = 0.0, SE = 0.0;
#pragma unroll
            for (int i = 0; i < 16; i++) { SL += TL[i]; SE += TE[i]; }
            double loss_cb = SL / (double)NELEM;     // == loss_commit numerically
            outsc[0] = (float)(loss_cb + 0.25 * loss_cb);
            outsc[1] = (float)exp(-SE);
        }
    }
}

extern "C" void kernel_launch(void* const* d_in, const int* in_sizes, int n_in,
                              void* d_out, int out_size, void* d_ws, size_t ws_size,
                              hipStream_t stream) {
    const float* ze = (const float*)d_in[0];
    const float* cb = (const float*)d_in[1];
    float* out = (float*)d_out;
    char* ws = (char*)d_ws;

    int*          hist = (int*)(ws + WS_HIST);
    float*        n32  = (float*)(ws + WS_CBN32);
    double*       part = (double*)(ws + WS_PART);
    unsigned int* ctr  = (unsigned int*)(ws + WS_CTR);
    __bf16*       cbbf = (__bf16*)(ws + WS_CBBF);

    float* zq      = out;                 // (32, 64, 2048)
    float* codes_f = out + NELEM;         // (32, 2048) as float
    float* outsc   = out + NELEM + NVEC;  // [loss_vq, perplexity]

    k_cbprep<<<16, 64, 0, stream>>>(cb, n32, cbbf, hist, ctr);  // + zero hist/ctr
    k_vq<<<NBLK, 512, 0, stream>>>(ze, cb, n32, cbbf, hist, codes_f, zq, part,
                                   ctr, outsc);
}

// Round 6
// 213.069 us; speedup vs baseline: 1.3032x; 1.3032x over previous
//
#include <hip/hip_runtime.h>
#include <math.h>

// Problem constants
#define NB 32
#define NC 64          // CODE_DIM
#define NK 2048
#define NCODES 1024
#define NVEC (NB*NK)          // 65536 vectors
#define NELEM (NB*NC*NK)      // 4194304 elements
#define NBLK2 2048            // 32 vectors per block

#define MARGIN 1.5e-3f        // rigorous bf16-proxy bound (validated R5)
#define CAP 32

// ws layout (bytes)
#define WS_HIST  0            // int[1024]      = 4096
#define WS_CBN32 4096         // float[1024]    = 4096
#define WS_PART  8192         // double[2048]   = 16384
#define WS_CTR   24576        // unsigned int   = 4
#define WS_CBBF  32768        // __bf16[65536]  = 131072

typedef __bf16 bf16x8 __attribute__((ext_vector_type(8)));
typedef float  f32x4  __attribute__((ext_vector_type(4)));
#define MFMA16(A, B, ACC) __builtin_amdgcn_mfma_f32_16x16x32_bf16(A, B, ACC, 0, 0, 0)

// --- codebook prep: numpy-exact fp32 norms (same summation order as validated
// version -> bit-identical n32) + bf16 copy; block 0 zeroes hist + ctr. ------
__global__ void k_cbprep(const float* __restrict__ cb, float* __restrict__ n32,
                         __bf16* __restrict__ cbbf, int* __restrict__ hist,
                         unsigned int* __restrict__ ctr) {
    const int t = threadIdx.x;
    const int j = blockIdx.x * 64 + t;   // 16 x 64 = 1024
    if (blockIdx.x == 0) {
        int4 z4; z4.x = 0; z4.y = 0; z4.z = 0; z4.w = 0;
#pragma unroll
        for (int i = 0; i < 4; i++) ((int4*)hist)[t * 4 + i] = z4;
        if (t == 0) *ctr = 0u;
    }
    const float* cr = cb + (size_t)j * NC;
    float x[64];
#pragma unroll
    for (int i = 0; i < 16; i++) {
        f32x4 tv = *(const f32x4*)(cr + 4 * i);
        x[4*i+0] = tv[0]; x[4*i+1] = tv[1]; x[4*i+2] = tv[2]; x[4*i+3] = tv[3];
    }
    // EXACT same chain as validated version (order preserved)
    float r[8];
#pragma unroll
    for (int q = 0; q < 8; q++) r[q] = __fmul_rn(x[q], x[q]);
#pragma unroll
    for (int i = 8; i < 64; i += 8)
#pragma unroll
        for (int q = 0; q < 8; q++)
            r[q] = __fadd_rn(r[q], __fmul_rn(x[i + q], x[i + q]));
    float s01 = __fadd_rn(r[0], r[1]), s23 = __fadd_rn(r[2], r[3]);
    float s45 = __fadd_rn(r[4], r[5]), s67 = __fadd_rn(r[6], r[7]);
    n32[j] = __fadd_rn(__fadd_rn(s01, s23), __fadd_rn(s45, s67));
    __bf16* br = cbbf + (size_t)j * NC;
#pragma unroll
    for (int i = 0; i < 8; i++) {
        bf16x8 o;
#pragma unroll
        for (int q = 0; q < 8; q++) o[q] = (__bf16)x[8*i + q];
        *(bf16x8*)(br + 8*i) = o;
    }
}

// --- fused VQ: full-occupancy WITHOUT a spill-inducing VGPR cap --------------
// Block: 256 thr = 4 waves; 32 vectors. Grid = 2048 blocks. launch_bounds
// (256,4) caps VGPR at 128 (no spills, guaranteed); the live set (~50 regs:
// af[2][2]=16, pmin 8, B-frags ~16) should land <=64, at which the HW grants
// 8 waves/SIMD -> 8 blocks/CU -> 32 waves/CU full occupancy. If the compiler
// lands >64 we degrade exactly to R2's occupancy (bounded downside).
// R4/R5 LESSON: min-waves=8 in launch_bounds forced a 64-VGPR cap below the
// live set -> scratch spills -> 270+ MB of HBM spill traffic. Never cap below
// the live set; let actual VGPR usage set occupancy.
// Wave w owns codes [w*256,(w+1)*256) = 16 tiles, B-frags streamed from L2.
// pd = fma(-2,acc,nvv) == sub(nvv,mul(2,acc)) bit-exact (validated R4).
// t1 computed once per vector by t<32 (validated-chain, R5-passed broadcast),
// overlapped with pass 2. Two-pass margin capture; exact fp32 rescore; fused
// last-block finalize (R4-passed 2048-partial reduction).
// MFMA 16x16x32 bf16 layout (validated R5): A[m=lane&15][k=quad*8+j];
// B[n=lane&15][k=quad*8+j]; D col=lane&15 (code), row=quad*4+reg (vector).
__launch_bounds__(256, 4)
__global__ void k_vq(const float* __restrict__ ze, const float* __restrict__ cb,
                     const float* __restrict__ n32, const __bf16* __restrict__ cbbf,
                     int* __restrict__ hist, float* __restrict__ codes_f,
                     float* __restrict__ outq, double* __restrict__ part,
                     unsigned int* __restrict__ ctr, float* __restrict__ outsc) {
    __shared__ float wmin[32][5];            // padded minor (bank spread)
    __shared__ float gthr[32];
    __shared__ float t1s[32];
    __shared__ int cnt[32];
    __shared__ int cand[32][CAP + 1];        // padded
    __shared__ unsigned long long keys2[32][9];  // padded
    __shared__ int codearr[32];
    __shared__ double lsd[4];
    __shared__ int lastflag;
    __shared__ double TL[32], TE[16];

    const int t = threadIdx.x;
    const int L = t & 63;
    const int w = t >> 6;            // wave 0..3
    const int quad = L >> 4;
    const int col = L & 15;
    const int vec0 = blockIdx.x * 32;
    const int b = vec0 >> 11;
    const int k0 = vec0 & (NK - 1);
    const float* zbase = ze + (size_t)b * NC * NK + k0;

    // ---- A-frags for this block's 32 vectors (reg-resident, 16 VGPR) -------
    bf16x8 af[2][2];
#pragma unroll
    for (int vt = 0; vt < 2; vt++)
#pragma unroll
        for (int kt = 0; kt < 2; kt++)
#pragma unroll
            for (int j = 0; j < 8; j++)
                af[vt][kt][j] =
                    (__bf16)zbase[(size_t)(kt*32 + quad*8 + j) * NK + vt*16 + col];

    // ---- pass 1: per-lane proxy min over wave's 256 codes ------------------
    float pmin[2][4];
#pragma unroll
    for (int vt = 0; vt < 2; vt++)
#pragma unroll
        for (int r = 0; r < 4; r++) pmin[vt][r] = 1e30f;
#pragma unroll 2
    for (int tile = 0; tile < 16; tile++) {   // unroll 2: cap live B-regs
        const __bf16* brow = cbbf + (size_t)(w*256 + tile*16 + col) * NC + quad*8;
        bf16x8 b0 = *(const bf16x8*)(brow);
        bf16x8 b1 = *(const bf16x8*)(brow + 32);
        float nvv = n32[w*256 + tile*16 + col];
#pragma unroll
        for (int vt = 0; vt < 2; vt++) {   // 2 independent MFMA chains
            f32x4 acc = {0.f, 0.f, 0.f, 0.f};
            acc = MFMA16(af[vt][0], b0, acc);
            acc = MFMA16(af[vt][1], b1, acc);
#pragma unroll
            for (int r = 0; r < 4; r++) {
                float pd = __fmaf_rn(-2.f, acc[r], nvv);  // == sub(nvv,mul(2,acc))
                pmin[vt][r] = fminf(pmin[vt][r], pd);
            }
        }
    }
    // one-time cross-col reduce
#pragma unroll
    for (int vt = 0; vt < 2; vt++)
#pragma unroll
        for (int r = 0; r < 4; r++) {
            float pm = pmin[vt][r];
            pm = fminf(pm, __shfl_xor(pm, 1, 16));
            pm = fminf(pm, __shfl_xor(pm, 2, 16));
            pm = fminf(pm, __shfl_xor(pm, 4, 16));
            pm = fminf(pm, __shfl_xor(pm, 8, 16));
            if (col == 0) wmin[vt*16 + quad*4 + r][w] = pm;
        }
    __syncthreads();

    if (t < 32) {
        float g = wmin[t][0];
#pragma unroll
        for (int ww = 1; ww < 4; ww++) g = fminf(g, wmin[t][ww]);
        gthr[t] = g + MARGIN;
        cnt[t] = 0;
    }
    __syncthreads();

    // ---- t<32: exact t1 per vector (validated chain, computed once) --------
    // Consumed only after the next __syncthreads(); other threads go straight
    // into pass 2 (R5-passed overlap pattern).
    if (t < 32) {
        const int v = t;
        float rr[8];
#pragma unroll
        for (int q = 0; q < 8; q++) {
            float xx = zbase[(size_t)q * NK + v];
            rr[q] = __fmul_rn(xx, xx);
        }
#pragma unroll
        for (int i = 8; i < 64; i += 8)
#pragma unroll
            for (int q = 0; q < 8; q++) {
                float xx = zbase[(size_t)(i + q) * NK + v];
                rr[q] = __fadd_rn(rr[q], __fmul_rn(xx, xx));
            }
        float s01 = __fadd_rn(rr[0], rr[1]), s23 = __fadd_rn(rr[2], rr[3]);
        float s45 = __fadd_rn(rr[4], rr[5]), s67 = __fadd_rn(rr[6], rr[7]);
        t1s[v] = __fadd_rn(__fadd_rn(s01, s23), __fadd_rn(s45, s67));
    }

    // ---- pass 2: capture candidates within MARGIN of global proxy min ------
    float thr[2][4];
#pragma unroll
    for (int vt = 0; vt < 2; vt++)
#pragma unroll
        for (int r = 0; r < 4; r++) thr[vt][r] = gthr[vt*16 + quad*4 + r];
#pragma unroll 2
    for (int tile = 0; tile < 16; tile++) {
        const __bf16* brow = cbbf + (size_t)(w*256 + tile*16 + col) * NC + quad*8;
        bf16x8 b0 = *(const bf16x8*)(brow);
        bf16x8 b1 = *(const bf16x8*)(brow + 32);
        float nvv = n32[w*256 + tile*16 + col];
#pragma unroll
        for (int vt = 0; vt < 2; vt++) {
            f32x4 acc = {0.f, 0.f, 0.f, 0.f};
            acc = MFMA16(af[vt][0], b0, acc);
            acc = MFMA16(af[vt][1], b1, acc);
#pragma unroll
            for (int r = 0; r < 4; r++) {
                float pd = __fmaf_rn(-2.f, acc[r], nvv);
                if (pd <= thr[vt][r]) {
                    int m = vt*16 + quad*4 + r;
                    int slot = atomicAdd(&cnt[m], 1);
                    if (slot < CAP) cand[m][slot] = w*256 + tile*16 + col;
                }
            }
        }
    }
    __syncthreads();

    // ---- exact rescore: 8 threads/vector, validated bit-exact fp32 chain ---
    {
        const int v = t & 31;          // vector; this thread handles part p
        const int p = t >> 5;          // 0..7
        const float t1 = t1s[v];
        int cc = cnt[v];
        unsigned long long kmin = 0xFFFFFFFFFFFFFFFFULL;
        if (cc <= CAP) {
            for (int si = p; si < cc; si += 8) {
                int j = cand[v][si];
                const float* cr = cb + (size_t)j * NC;
                float a = 0.f;
#pragma unroll
                for (int c = 0; c < NC; c++)
                    a = __fmaf_rn(zbase[(size_t)c * NK + v], cr[c], a);
                float d = __fmaf_rn(-2.f, a, __fadd_rn(t1, n32[j]));
                unsigned long long key =
                    ((unsigned long long)__float_as_uint(d) << 32) | (unsigned int)j;
                if (key < kmin) kmin = key;
            }
        } else {   // overflow fallback: exact full scan split over 8 groups
            for (int j = p * 128; j < (p + 1) * 128; j++) {
                const float* cr = cb + (size_t)j * NC;
                float a = 0.f;
#pragma unroll
                for (int c = 0; c < NC; c++)
                    a = __fmaf_rn(zbase[(size_t)c * NK + v], cr[c], a);
                float d = __fmaf_rn(-2.f, a, __fadd_rn(t1, n32[j]));
                unsigned long long key =
                    ((unsigned long long)__float_as_uint(d) << 32) | (unsigned int)j;
                if (key < kmin) kmin = key;
            }
        }
        keys2[v][p] = kmin;
    }
    __syncthreads();

    if (t < 32) {   // merge 8 partial keys: min dist, ties -> min idx (np rule)
        unsigned long long kmin = keys2[t][0];
#pragma unroll
        for (int pp = 1; pp < 8; pp++) {
            unsigned long long kk = keys2[t][pp];
            if (kk < kmin) kmin = kk;
        }
        int code = (int)(kmin & 0xFFFFFFFFu);
        codearr[t] = code;
        codes_f[vec0 + t] = (float)code;
        atomicAdd(&hist[code], 1);
    }
    __syncthreads();

    // ---- quant epilogue: float4; per (b,c) row 8 thr x 16B = 128B aligned --
    double s = 0.0;
    float* ob = outq + (size_t)b * NC * NK + k0;
    const int c0 = t >> 3;             // 0..31
    const int v0 = (t & 7) * 4;        // 0,4,..,28
    int cds[4];
#pragma unroll
    for (int u = 0; u < 4; u++) cds[u] = codearr[v0 + u];
#pragma unroll
    for (int half = 0; half < 2; half++) {
        const int c = c0 + half * 32;
        f32x4 zv = *(const f32x4*)(zbase + (size_t)c * NK + v0);
        f32x4 ov;
#pragma unroll
        for (int u = 0; u < 4; u++) {
            float qv = cb[(size_t)cds[u] * NC + c];
            ov[u] = __fadd_rn(zv[u], __fsub_rn(qv, zv[u]));
            double d = (double)qv - (double)zv[u];
            s += d * d;
        }
        *(f32x4*)(ob + (size_t)c * NK + v0) = ov;
    }
    for (int off = 32; off; off >>= 1) s += __shfl_down(s, off);
    if (L == 0) lsd[w] = s;
    __syncthreads();
    if (t == 0) {
        double tot = lsd[0] + lsd[1] + lsd[2] + lsd[3];
        part[blockIdx.x] = tot;
        __threadfence();                             // part+hist visible first
        unsigned int my = atomicAdd(ctr, 1u);
        lastflag = (my == NBLK2 - 1) ? 1 : 0;
    }
    __syncthreads();

    // ---- last block: finalize (R4-passed 2048-partial reduction) -----------
    if (lastflag) {
        __threadfence();   // acquire side
        // loss: 32 groups of 64 partials; wave w handles groups w,w+4,...,w+28
#pragma unroll
        for (int gi = 0; gi < 8; gi++) {
            int g = w + gi * 4;
            double vL = part[g * 64 + L];
            for (int off = 32; off; off >>= 1) vL += __shfl_down(vL, off);
            if (L == 0) TL[g] = vL;
        }
        // perplexity: 16 groups of 64 hist bins (identical to old k_final)
#pragma unroll
        for (int gi = 0; gi < 4; gi++) {
            int g = w + gi * 4;
            double pp = (double)hist[g * 64 + L] * (1.0 / (double)NVEC);
            double vE = pp * log(pp + 1e-10);
            for (int off = 32; off; off >>= 1) vE += __shfl_down(vE, off);
            if (L == 0) TE[g] = vE;
        }
        __syncthreads();
        if (t == 0) {
            double SL = 0.0, SE = 0.0;
#pragma unroll
            for (int i = 0; i < 32; i++) SL += TL[i];
#pragma unroll
            for (int i = 0; i < 16; i++) SE += TE[i];
            double loss_cb = SL / (double)NELEM;     // == loss_commit numerically
            outsc[0] = (float)(loss_cb + 0.25 * loss_cb);
            outsc[1] = (float)exp(-SE);
        }
    }
}

extern "C" void kernel_launch(void* const* d_in, const int* in_sizes, int n_in,
                              void* d_out, int out_size, void* d_ws, size_t ws_size,
                              hipStream_t stream) {
    const float* ze = (const float*)d_in[0];
    const float* cb = (const float*)d_in[1];
    float* out = (float*)d_out;
    char* ws = (char*)d_ws;

    int*          hist = (int*)(ws + WS_HIST);
    float*        n32  = (float*)(ws + WS_CBN32);
    double*       part = (double*)(ws + WS_PART);
    unsigned int* ctr  = (unsigned int*)(ws + WS_CTR);
    __bf16*       cbbf = (__bf16*)(ws + WS_CBBF);

    float* zq      = out;                 // (32, 64, 2048)
    float* codes_f = out + NELEM;         // (32, 2048) as float
    float* outsc   = out + NELEM + NVEC;  // [loss_vq, perplexity]

    k_cbprep<<<16, 64, 0, stream>>>(cb, n32, cbbf, hist, ctr);  // + zero hist/ctr
    k_vq<<<NBLK2, 256, 0, stream>>>(ze, cb, n32, cbbf, hist, codes_f, zq, part,
                                    ctr, outsc);
}

// Round 8
// 153.706 us; speedup vs baseline: 1.8065x; 1.3862x over previous
//
#include <hip/hip_runtime.h>
#include <math.h>

// Problem constants
#define NB 32
#define NC 64          // CODE_DIM
#define NK 2048
#define NCODES 1024
#define NVEC (NB*NK)          // 65536 vectors
#define NELEM (NB*NC*NK)      // 4194304 elements
#define NBLK 1024             // 64 vectors per block (R2 shape: the winner)

#define MARGIN 1.5e-3f        // rigorous bf16-proxy bound (validated R5)
#define CAP 32

// ws layout (bytes)
#define WS_HIST  0            // int[1024]      = 4096
#define WS_CBN32 4096         // float[1024]    = 4096
#define WS_PART  8192         // double[1024]   = 8192
#define WS_CTR   24576        // unsigned int   = 4
#define WS_CBBF  32768        // __bf16[65536]  = 131072

typedef __bf16 bf16x8 __attribute__((ext_vector_type(8)));
typedef float  f32x4  __attribute__((ext_vector_type(4)));
#define MFMA16(A, B, ACC) __builtin_amdgcn_mfma_f32_16x16x32_bf16(A, B, ACC, 0, 0, 0)

// --- codebook prep: numpy-exact fp32 norms (same summation order as validated
// version -> bit-identical n32) + bf16 copy; block 0 zeroes hist + ctr. ------
__global__ void k_cbprep(const float* __restrict__ cb, float* __restrict__ n32,
                         __bf16* __restrict__ cbbf, int* __restrict__ hist,
                         unsigned int* __restrict__ ctr) {
    const int t = threadIdx.x;
    const int j = blockIdx.x * 64 + t;   // 16 x 64 = 1024
    if (blockIdx.x == 0) {
        int4 z4; z4.x = 0; z4.y = 0; z4.z = 0; z4.w = 0;
#pragma unroll
        for (int i = 0; i < 4; i++) ((int4*)hist)[t * 4 + i] = z4;
        if (t == 0) *ctr = 0u;
    }
    const float* cr = cb + (size_t)j * NC;
    float x[64];
#pragma unroll
    for (int i = 0; i < 16; i++) {
        f32x4 tv = *(const f32x4*)(cr + 4 * i);
        x[4*i+0] = tv[0]; x[4*i+1] = tv[1]; x[4*i+2] = tv[2]; x[4*i+3] = tv[3];
    }
    // EXACT same chain as validated version (order preserved)
    float r[8];
#pragma unroll
    for (int q = 0; q < 8; q++) r[q] = __fmul_rn(x[q], x[q]);
#pragma unroll
    for (int i = 8; i < 64; i += 8)
#pragma unroll
        for (int q = 0; q < 8; q++)
            r[q] = __fadd_rn(r[q], __fmul_rn(x[i + q], x[i + q]));
    float s01 = __fadd_rn(r[0], r[1]), s23 = __fadd_rn(r[2], r[3]);
    float s45 = __fadd_rn(r[4], r[5]), s67 = __fadd_rn(r[6], r[7]);
    n32[j] = __fadd_rn(__fadd_rn(s01, s23), __fadd_rn(s45, s67));
    __bf16* br = cbbf + (size_t)j * NC;
#pragma unroll
    for (int i = 0; i < 8; i++) {
        bf16x8 o;
#pragma unroll
        for (int q = 0; q < 8; q++) o[q] = (__bf16)x[8*i + q];
        *(bf16x8*)(br + 8*i) = o;
    }
}

// --- fused VQ: R2's measured-best structure + validated deltas only ----------
// Block: 256 thr = 4 waves; 64 vectors; grid 1024. This is the R2 kernel that
// measured 63us (VGPR 56, 4 blocks/CU) -- the empirical optimum across R1-R6.
// LESSONS BANKED: (R1) 8-wave blocks -> 1 blk/CU; (R3) LDS z-staging -> +26us
// bank conflicts; (R4/R5) forced VGPR caps -> catastrophic spills (270MB
// scratch traffic); (R6) 32-vec blocks -> halved per-wave efficiency, slower
// even at higher occupancy. DO NOT touch the hot-loop shape.
// Deltas vs R2 (each validated in a passing run): fma(-2,acc,nvv) contraction
// (R4+), wave-0 t1 broadcast overlapped with pass 2 (R5+), fused last-block
// finalize exact k_final replica (R3+), padded LDS minor strides (R3+).
// MFMA 16x16x32 bf16 layout (validated R5): A[m=lane&15][k=quad*8+j];
// B[n=lane&15][k=quad*8+j]; D col=lane&15 (code), row=quad*4+reg (vector).
__launch_bounds__(256, 4)
__global__ void k_vq(const float* __restrict__ ze, const float* __restrict__ cb,
                     const float* __restrict__ n32, const __bf16* __restrict__ cbbf,
                     int* __restrict__ hist, float* __restrict__ codes_f,
                     float* __restrict__ outq, double* __restrict__ part,
                     unsigned int* __restrict__ ctr, float* __restrict__ outsc) {
    __shared__ float wmin[64][5];            // padded minor (bank spread)
    __shared__ float gthr[64];
    __shared__ float t1s[64];
    __shared__ int cnt[64];
    __shared__ int cand[64][CAP + 1];        // padded
    __shared__ unsigned long long keys2[64][5];  // padded
    __shared__ int codearr[64];
    __shared__ double lsd[4];
    __shared__ int lastflag;
    __shared__ double TL[16], TE[16];

    const int t = threadIdx.x;
    const int L = t & 63;
    const int w = t >> 6;            // wave 0..3
    const int quad = L >> 4;
    const int col = L & 15;
    const int vec0 = blockIdx.x * 64;
    const int b = vec0 >> 11;
    const int k0 = vec0 & (NK - 1);
    const float* zbase = ze + (size_t)b * NC * NK + k0;

    // ---- A-frags for all 64 vectors (reg-resident, 32 VGPR) ----------------
    bf16x8 af[4][2];
#pragma unroll
    for (int vt = 0; vt < 4; vt++)
#pragma unroll
        for (int kt = 0; kt < 2; kt++)
#pragma unroll
            for (int j = 0; j < 8; j++)
                af[vt][kt][j] =
                    (__bf16)zbase[(size_t)(kt*32 + quad*8 + j) * NK + vt*16 + col];

    // ---- pass 1: per-lane proxy min over wave's 256 codes ------------------
    float pmin[4][4];
#pragma unroll
    for (int vt = 0; vt < 4; vt++)
#pragma unroll
        for (int r = 0; r < 4; r++) pmin[vt][r] = 1e30f;
#pragma unroll 4
    for (int tile = 0; tile < 16; tile++) {   // unroll 4: limit B-load hoisting
        const __bf16* brow = cbbf + (size_t)(w*256 + tile*16 + col) * NC + quad*8;
        bf16x8 b0 = *(const bf16x8*)(brow);
        bf16x8 b1 = *(const bf16x8*)(brow + 32);
        float nvv = n32[w*256 + tile*16 + col];
#pragma unroll
        for (int vt = 0; vt < 4; vt++) {   // 4 independent MFMA chains (ILP)
            f32x4 acc = {0.f, 0.f, 0.f, 0.f};
            acc = MFMA16(af[vt][0], b0, acc);
            acc = MFMA16(af[vt][1], b1, acc);
#pragma unroll
            for (int r = 0; r < 4; r++) {
                float pd = __fmaf_rn(-2.f, acc[r], nvv);  // == sub(nvv,mul(2,acc))
                pmin[vt][r] = fminf(pmin[vt][r], pd);
            }
        }
    }
    // one-time cross-col reduce
#pragma unroll
    for (int vt = 0; vt < 4; vt++)
#pragma unroll
        for (int r = 0; r < 4; r++) {
            float pm = pmin[vt][r];
            pm = fminf(pm, __shfl_xor(pm, 1, 16));
            pm = fminf(pm, __shfl_xor(pm, 2, 16));
            pm = fminf(pm, __shfl_xor(pm, 4, 16));
            pm = fminf(pm, __shfl_xor(pm, 8, 16));
            if (col == 0) wmin[vt*16 + quad*4 + r][w] = pm;
        }
    __syncthreads();

    if (t < 64) {
        float g = wmin[t][0];
#pragma unroll
        for (int ww = 1; ww < 4; ww++) g = fminf(g, wmin[t][ww]);
        gthr[t] = g + MARGIN;
        cnt[t] = 0;
    }
    __syncthreads();

    // ---- wave 0: exact t1 per vector (validated chain, computed once) ------
    // Consumed only after the next __syncthreads(); waves 1-3 go straight into
    // pass 2 (R5/R6-passed overlap pattern).
    if (t < 64) {
        const int v = t;
        float rr[8];
#pragma unroll
        for (int q = 0; q < 8; q++) {
            float xx = zbase[(size_t)q * NK + v];
            rr[q] = __fmul_rn(xx, xx);
        }
#pragma unroll
        for (int i = 8; i < 64; i += 8)
#pragma unroll
            for (int q = 0; q < 8; q++) {
                float xx = zbase[(size_t)(i + q) * NK + v];
                rr[q] = __fadd_rn(rr[q], __fmul_rn(xx, xx));
            }
        float s01 = __fadd_rn(rr[0], rr[1]), s23 = __fadd_rn(rr[2], rr[3]);
        float s45 = __fadd_rn(rr[4], rr[5]), s67 = __fadd_rn(rr[6], rr[7]);
        t1s[v] = __fadd_rn(__fadd_rn(s01, s23), __fadd_rn(s45, s67));
    }

    // ---- pass 2: capture candidates within MARGIN of global proxy min ------
    float thr[4][4];
#pragma unroll
    for (int vt = 0; vt < 4; vt++)
#pragma unroll
        for (int r = 0; r < 4; r++) thr[vt][r] = gthr[vt*16 + quad*4 + r];
#pragma unroll 4
    for (int tile = 0; tile < 16; tile++) {
        const __bf16* brow = cbbf + (size_t)(w*256 + tile*16 + col) * NC + quad*8;
        bf16x8 b0 = *(const bf16x8*)(brow);
        bf16x8 b1 = *(const bf16x8*)(brow + 32);
        float nvv = n32[w*256 + tile*16 + col];
#pragma unroll
        for (int vt = 0; vt < 4; vt++) {
            f32x4 acc = {0.f, 0.f, 0.f, 0.f};
            acc = MFMA16(af[vt][0], b0, acc);
            acc = MFMA16(af[vt][1], b1, acc);
#pragma unroll
            for (int r = 0; r < 4; r++) {
                float pd = __fmaf_rn(-2.f, acc[r], nvv);
                if (pd <= thr[vt][r]) {
                    int m = vt*16 + quad*4 + r;
                    int slot = atomicAdd(&cnt[m], 1);
                    if (slot < CAP) cand[m][slot] = w*256 + tile*16 + col;
                }
            }
        }
    }
    __syncthreads();

    // ---- exact rescore: 4 threads/vector, validated bit-exact fp32 chain ---
    {
        const int v = L;               // vector; this thread handles part w
        const float t1 = t1s[v];
        int cc = cnt[v];
        unsigned long long kmin = 0xFFFFFFFFFFFFFFFFULL;
        if (cc <= CAP) {
            for (int si = w; si < cc; si += 4) {
                int j = cand[v][si];
                const float* cr = cb + (size_t)j * NC;
                float a = 0.f;
#pragma unroll
                for (int c = 0; c < NC; c++)
                    a = __fmaf_rn(zbase[(size_t)c * NK + v], cr[c], a);
                float d = __fmaf_rn(-2.f, a, __fadd_rn(t1, n32[j]));
                unsigned long long key =
                    ((unsigned long long)__float_as_uint(d) << 32) | (unsigned int)j;
                if (key < kmin) kmin = key;
            }
        } else {   // overflow fallback: exact full scan split over 4 threads
            for (int j = w * 256; j < (w + 1) * 256; j++) {
                const float* cr = cb + (size_t)j * NC;
                float a = 0.f;
#pragma unroll
                for (int c = 0; c < NC; c++)
                    a = __fmaf_rn(zbase[(size_t)c * NK + v], cr[c], a);
                float d = __fmaf_rn(-2.f, a, __fadd_rn(t1, n32[j]));
                unsigned long long key =
                    ((unsigned long long)__float_as_uint(d) << 32) | (unsigned int)j;
                if (key < kmin) kmin = key;
            }
        }
        keys2[v][w] = kmin;
    }
    __syncthreads();

    if (t < 64) {   // merge 4 partial keys: min dist, ties -> min idx (np rule)
        unsigned long long kmin = keys2[t][0];
#pragma unroll
        for (int ww = 1; ww < 4; ww++) {
            unsigned long long kk = keys2[t][ww];
            if (kk < kmin) kmin = kk;
        }
        int code = (int)(kmin & 0xFFFFFFFFu);
        codearr[t] = code;
        codes_f[vec0 + t] = (float)code;
        atomicAdd(&hist[code], 1);
    }
    __syncthreads();

    // ---- quant epilogue: float4; per c-row 16 thr x 16B = 256B contiguous --
    double s = 0.0;
    float* ob = outq + (size_t)b * NC * NK + k0;
    const int c0 = t >> 4;             // 0..15
    const int v0 = (t & 15) * 4;       // 0,4,..,60
    int cds[4];
#pragma unroll
    for (int u = 0; u < 4; u++) cds[u] = codearr[v0 + u];
#pragma unroll
    for (int half = 0; half < 4; half++) {
        const int c = c0 + half * 16;
        f32x4 zv = *(const f32x4*)(zbase + (size_t)c * NK + v0);
        f32x4 ov;
#pragma unroll
        for (int u = 0; u < 4; u++) {
            float qv = cb[(size_t)cds[u] * NC + c];
            ov[u] = __fadd_rn(zv[u], __fsub_rn(qv, zv[u]));
            double d = (double)qv - (double)zv[u];
            s += d * d;
        }
        *(f32x4*)(ob + (size_t)c * NK + v0) = ov;
    }
    for (int off = 32; off; off >>= 1) s += __shfl_down(s, off);
    if (L == 0) lsd[w] = s;
    __syncthreads();
    if (t == 0) {
        double tot = lsd[0] + lsd[1] + lsd[2] + lsd[3];
        part[blockIdx.x] = tot;
        __threadfence();                             // part+hist visible first
        unsigned int my = atomicAdd(ctr, 1u);
        lastflag = (my == NBLK - 1) ? 1 : 0;
    }
    __syncthreads();

    // ---- last block: finalize (exact replica of old k_final reduction) -----
    if (lastflag) {
        __threadfence();   // acquire side
        // wave w tree-reduces part-groups {w, w+4, w+8, w+12} with the SAME
        // 64-lane shfl_down tree as old k_final; t0 sums groups 0..15 in order
#pragma unroll
        for (int gi = 0; gi < 4; gi++) {
            int g = w + gi * 4;
            double vL = part[g * 64 + L];
            double pp = (double)hist[g * 64 + L] * (1.0 / (double)NVEC);
            double vE = pp * log(pp + 1e-10);
            for (int off = 32; off; off >>= 1) {
                vL += __shfl_down(vL, off);
                vE += __shfl_down(vE, off);
            }
            if (L == 0) { TL[g] = vL; TE[g] = vE; }
        }
        __syncthreads();
        if (t == 0) {
            double SL = 0.0, SE = 0.0;
#pragma unroll
            for (int i = 0; i < 16; i++) { SL += TL[i]; SE += TE[i]; }
            double loss_cb = SL / (double)NELEM;     // == loss_commit numerically
            outsc[0] = (float)(loss_cb + 0.25 * loss_cb);
            outsc[1] = (float)exp(-SE);
        }
    }
}

extern "C" void kernel_launch(void* const* d_in, const int* in_sizes, int n_in,
                              void* d_out, int out_size, void* d_ws, size_t ws_size,
                              hipStream_t stream) {
    const float* ze = (const float*)d_in[0];
    const float* cb = (const float*)d_in[1];
    float* out = (float*)d_out;
    char* ws = (char*)d_ws;

    int*          hist = (int*)(ws + WS_HIST);
    float*        n32  = (float*)(ws + WS_CBN32);
    double*       part = (double*)(ws + WS_PART);
    unsigned int* ctr  = (unsigned int*)(ws + WS_CTR);
    __bf16*       cbbf = (__bf16*)(ws + WS_CBBF);

    float* zq      = out;                 // (32, 64, 2048)
    float* codes_f = out + NELEM;         // (32, 2048) as float
    float* outsc   = out + NELEM + NVEC;  // [loss_vq, perplexity]

    k_cbprep<<<16, 64, 0, stream>>>(cb, n32, cbbf, hist, ctr);  // + zero hist/ctr
    k_vq<<<NBLK, 256, 0, stream>>>(ze, cb, n32, cbbf, hist, codes_f, zq, part,
                                   ctr, outsc);
}

// Round 9
// 127.994 us; speedup vs baseline: 2.1694x; 1.2009x over previous
//
#include <hip/hip_runtime.h>
#include <math.h>

// Problem constants
#define NB 32
#define NC 64          // CODE_DIM
#define NK 2048
#define NCODES 1024
#define NVEC (NB*NK)          // 65536 vectors
#define NELEM (NB*NC*NK)      // 4194304 elements
#define NBLK (NVEC/64)        // 1024 blocks

#define MARGIN 1.5e-3f        // rigorous bf16-proxy bound (validated R5)
#define CAP 32

// ws layout (bytes)
#define WS_HIST  0            // int[1024]      = 4096
#define WS_CBN32 4096         // float[1024]    = 4096
#define WS_PART  8192         // double[1024]   = 8192
#define WS_CBBF  32768        // __bf16[65536]  = 131072

typedef __bf16 bf16x8 __attribute__((ext_vector_type(8)));
typedef float  f32x4  __attribute__((ext_vector_type(4)));
#define MFMA16(A, B, ACC) __builtin_amdgcn_mfma_f32_16x16x32_bf16(A, B, ACC, 0, 0, 0)

// --- codebook prep: numpy-exact fp32 norms (same summation order as validated
// version -> bit-identical n32) + bf16 copy; block 0 zeroes hist. ------------
__global__ void k_cbprep(const float* __restrict__ cb, float* __restrict__ n32,
                         __bf16* __restrict__ cbbf, int* __restrict__ hist) {
    const int t = threadIdx.x;
    const int j = blockIdx.x * 64 + t;   // 16 x 64 = 1024
    if (blockIdx.x == 0) {
        int4 z4; z4.x = 0; z4.y = 0; z4.z = 0; z4.w = 0;
#pragma unroll
        for (int i = 0; i < 4; i++) ((int4*)hist)[t * 4 + i] = z4;
    }
    const float* cr = cb + (size_t)j * NC;
    float x[64];
#pragma unroll
    for (int i = 0; i < 16; i++) {
        f32x4 tv = *(const f32x4*)(cr + 4 * i);
        x[4*i+0] = tv[0]; x[4*i+1] = tv[1]; x[4*i+2] = tv[2]; x[4*i+3] = tv[3];
    }
    // EXACT same chain as validated version (order preserved)
    float r[8];
#pragma unroll
    for (int q = 0; q < 8; q++) r[q] = __fmul_rn(x[q], x[q]);
#pragma unroll
    for (int i = 8; i < 64; i += 8)
#pragma unroll
        for (int q = 0; q < 8; q++)
            r[q] = __fadd_rn(r[q], __fmul_rn(x[i + q], x[i + q]));
    float s01 = __fadd_rn(r[0], r[1]), s23 = __fadd_rn(r[2], r[3]);
    float s45 = __fadd_rn(r[4], r[5]), s67 = __fadd_rn(r[6], r[7]);
    n32[j] = __fadd_rn(__fadd_rn(s01, s23), __fadd_rn(s45, s67));
    __bf16* br = cbbf + (size_t)j * NC;
#pragma unroll
    for (int i = 0; i < 8; i++) {
        bf16x8 o;
#pragma unroll
        for (int q = 0; q < 8; q++) o[q] = (__bf16)x[8*i + q];
        *(bf16x8*)(br + 8*i) = o;
    }
}

// --- fused VQ: R2's measured-best kernel (63us) + fma contraction + padding --
// Block: 256 thr = 4 waves; 64 vectors; grid 1024. Byte-faithful to the R2
// winner: all-thread redundant t1 in the rescore phase, separate k_final
// dispatch (NO per-block __threadfence -- R8 LESSON: on multi-XCD gfx950 a
// device-scope release fence forces an L2 writeback per block; 1024 of them
// cost ~29us. Cross-block reduction belongs in its own tiny dispatch).
// Other banked lessons: (R1) 8-wave blocks -> 1 blk/CU; (R3) LDS z-staging ->
// bank-conflict blowup; (R4/R5) forced VGPR caps -> scratch spills; (R6)
// 32-vec blocks -> halved per-wave efficiency. DO NOT touch hot-loop shape.
// Deltas vs R2 (only two, both evidence-backed): pd = fma(-2,acc,nvv)
// (bit-exact == sub(nvv,mul(2,acc)), validated R4-R8; -1/3 hot-loop VALU) and
// padded LDS minor strides (conflicts 165k -> ~1k, validated R8).
// MFMA 16x16x32 bf16 layout (validated R5): A[m=lane&15][k=quad*8+j];
// B[n=lane&15][k=quad*8+j]; D col=lane&15 (code), row=quad*4+reg (vector).
__launch_bounds__(256, 4)
__global__ void k_vq(const float* __restrict__ ze, const float* __restrict__ cb,
                     const float* __restrict__ n32, const __bf16* __restrict__ cbbf,
                     int* __restrict__ hist, float* __restrict__ codes_f,
                     float* __restrict__ outq, double* __restrict__ part) {
    __shared__ float wmin[64][5];            // padded minor (bank spread)
    __shared__ float gthr[64];
    __shared__ int cnt[64];
    __shared__ int cand[64][CAP + 1];        // padded
    __shared__ unsigned long long keys2[64][5];  // padded
    __shared__ int codearr[64];
    __shared__ double lsd[4];

    const int t = threadIdx.x;
    const int L = t & 63;
    const int w = t >> 6;            // wave 0..3
    const int quad = L >> 4;
    const int col = L & 15;
    const int vec0 = blockIdx.x * 64;
    const int b = vec0 >> 11;
    const int k0 = vec0 & (NK - 1);
    const float* zbase = ze + (size_t)b * NC * NK + k0;

    // ---- A-frags for all 64 vectors (reg-resident, 32 VGPR) ----------------
    bf16x8 af[4][2];
#pragma unroll
    for (int vt = 0; vt < 4; vt++)
#pragma unroll
        for (int kt = 0; kt < 2; kt++)
#pragma unroll
            for (int j = 0; j < 8; j++)
                af[vt][kt][j] =
                    (__bf16)zbase[(size_t)(kt*32 + quad*8 + j) * NK + vt*16 + col];

    // ---- pass 1: per-lane proxy min over wave's 256 codes ------------------
    float pmin[4][4];
#pragma unroll
    for (int vt = 0; vt < 4; vt++)
#pragma unroll
        for (int r = 0; r < 4; r++) pmin[vt][r] = 1e30f;
#pragma unroll 4
    for (int tile = 0; tile < 16; tile++) {   // unroll 4: limit B-load hoisting
        const __bf16* brow = cbbf + (size_t)(w*256 + tile*16 + col) * NC + quad*8;
        bf16x8 b0 = *(const bf16x8*)(brow);
        bf16x8 b1 = *(const bf16x8*)(brow + 32);
        float nvv = n32[w*256 + tile*16 + col];
#pragma unroll
        for (int vt = 0; vt < 4; vt++) {   // 4 independent MFMA chains (ILP)
            f32x4 acc = {0.f, 0.f, 0.f, 0.f};
            acc = MFMA16(af[vt][0], b0, acc);
            acc = MFMA16(af[vt][1], b1, acc);
#pragma unroll
            for (int r = 0; r < 4; r++) {
                float pd = __fmaf_rn(-2.f, acc[r], nvv);  // == sub(nvv,mul(2,acc))
                pmin[vt][r] = fminf(pmin[vt][r], pd);
            }
        }
    }
    // one-time cross-col reduce
#pragma unroll
    for (int vt = 0; vt < 4; vt++)
#pragma unroll
        for (int r = 0; r < 4; r++) {
            float pm = pmin[vt][r];
            pm = fminf(pm, __shfl_xor(pm, 1, 16));
            pm = fminf(pm, __shfl_xor(pm, 2, 16));
            pm = fminf(pm, __shfl_xor(pm, 4, 16));
            pm = fminf(pm, __shfl_xor(pm, 8, 16));
            if (col == 0) wmin[vt*16 + quad*4 + r][w] = pm;
        }
    __syncthreads();

    if (t < 64) {
        float g = wmin[t][0];
#pragma unroll
        for (int ww = 1; ww < 4; ww++) g = fminf(g, wmin[t][ww]);
        gthr[t] = g + MARGIN;
        cnt[t] = 0;
    }
    __syncthreads();

    // ---- pass 2: capture candidates within MARGIN of global proxy min ------
    float thr[4][4];
#pragma unroll
    for (int vt = 0; vt < 4; vt++)
#pragma unroll
        for (int r = 0; r < 4; r++) thr[vt][r] = gthr[vt*16 + quad*4 + r];
#pragma unroll 4
    for (int tile = 0; tile < 16; tile++) {
        const __bf16* brow = cbbf + (size_t)(w*256 + tile*16 + col) * NC + quad*8;
        bf16x8 b0 = *(const bf16x8*)(brow);
        bf16x8 b1 = *(const bf16x8*)(brow + 32);
        float nvv = n32[w*256 + tile*16 + col];
#pragma unroll
        for (int vt = 0; vt < 4; vt++) {
            f32x4 acc = {0.f, 0.f, 0.f, 0.f};
            acc = MFMA16(af[vt][0], b0, acc);
            acc = MFMA16(af[vt][1], b1, acc);
#pragma unroll
            for (int r = 0; r < 4; r++) {
                float pd = __fmaf_rn(-2.f, acc[r], nvv);
                if (pd <= thr[vt][r]) {
                    int m = vt*16 + quad*4 + r;
                    int slot = atomicAdd(&cnt[m], 1);
                    if (slot < CAP) cand[m][slot] = w*256 + tile*16 + col;
                }
            }
        }
    }
    __syncthreads();

    // ---- exact rescore: 4 threads/vector, validated bit-exact fp32 chain ---
    {
        const int v = L;           // vector; this thread handles part w
        // t1 = np.sum(z*z), numpy-exact (redundant x4, bit-identical -- R2)
        float rr[8];
#pragma unroll
        for (int q = 0; q < 8; q++) {
            float xx = zbase[(size_t)q * NK + v];
            rr[q] = __fmul_rn(xx, xx);
        }
#pragma unroll
        for (int i = 8; i < 64; i += 8)
#pragma unroll
            for (int q = 0; q < 8; q++) {
                float xx = zbase[(size_t)(i + q) * NK + v];
                rr[q] = __fadd_rn(rr[q], __fmul_rn(xx, xx));
            }
        float s01 = __fadd_rn(rr[0], rr[1]), s23 = __fadd_rn(rr[2], rr[3]);
        float s45 = __fadd_rn(rr[4], rr[5]), s67 = __fadd_rn(rr[6], rr[7]);
        float t1 = __fadd_rn(__fadd_rn(s01, s23), __fadd_rn(s45, s67));

        int cc = cnt[v];
        unsigned long long kmin = 0xFFFFFFFFFFFFFFFFULL;
        if (cc <= CAP) {
            for (int si = w; si < cc; si += 4) {
                int j = cand[v][si];
                const float* cr = cb + (size_t)j * NC;
                float a = 0.f;
#pragma unroll
                for (int c = 0; c < NC; c++)
                    a = __fmaf_rn(zbase[(size_t)c * NK + v], cr[c], a);
                float d = __fmaf_rn(-2.f, a, __fadd_rn(t1, n32[j]));
                unsigned long long key =
                    ((unsigned long long)__float_as_uint(d) << 32) | (unsigned int)j;
                if (key < kmin) kmin = key;
            }
        } else {   // overflow fallback: exact full scan split over 4 threads
            for (int j = w * 256; j < (w + 1) * 256; j++) {
                const float* cr = cb + (size_t)j * NC;
                float a = 0.f;
#pragma unroll
                for (int c = 0; c < NC; c++)
                    a = __fmaf_rn(zbase[(size_t)c * NK + v], cr[c], a);
                float d = __fmaf_rn(-2.f, a, __fadd_rn(t1, n32[j]));
                unsigned long long key =
                    ((unsigned long long)__float_as_uint(d) << 32) | (unsigned int)j;
                if (key < kmin) kmin = key;
            }
        }
        keys2[v][w] = kmin;
    }
    __syncthreads();

    if (t < 64) {   // merge 4 partial keys: min dist, ties -> min idx (np rule)
        unsigned long long kmin = keys2[t][0];
#pragma unroll
        for (int ww = 1; ww < 4; ww++) {
            unsigned long long kk = keys2[t][ww];
            if (kk < kmin) kmin = kk;
        }
        int code = (int)(kmin & 0xFFFFFFFFu);
        codearr[t] = code;
        codes_f[vec0 + t] = (float)code;
        atomicAdd(&hist[code], 1);
    }
    __syncthreads();

    // ---- quant epilogue: float4; per c-row 16 thr x 16B = 256B contiguous --
    double s = 0.0;
    float* ob = outq + (size_t)b * NC * NK + k0;
    const int c0 = t >> 4;             // 0..15
    const int v0 = (t & 15) * 4;       // 0,4,..,60
    int cds[4];
#pragma unroll
    for (int u = 0; u < 4; u++) cds[u] = codearr[v0 + u];
#pragma unroll
    for (int half = 0; half < 4; half++) {
        const int c = c0 + half * 16;
        f32x4 zv = *(const f32x4*)(zbase + (size_t)c * NK + v0);
        f32x4 ov;
#pragma unroll
        for (int u = 0; u < 4; u++) {
            float qv = cb[(size_t)cds[u] * NC + c];
            ov[u] = __fadd_rn(zv[u], __fsub_rn(qv, zv[u]));
            double d = (double)qv - (double)zv[u];
            s += d * d;
        }
        *(f32x4*)(ob + (size_t)c * NK + v0) = ov;
    }
    for (int off = 32; off; off >>= 1) s += __shfl_down(s, off);
    if (L == 0) lsd[w] = s;
    __syncthreads();
    if (t == 0) part[blockIdx.x] = lsd[0] + lsd[1] + lsd[2] + lsd[3];
}

// --- final scalars: loss_vq and perplexity (separate dispatch: R8 lesson) ---
__launch_bounds__(1024)
__global__ void k_final(const double* __restrict__ part, const int* __restrict__ hist,
                        float* __restrict__ out) {
    int t = threadIdx.x;                         // 1024 threads = NBLK partials
    double vL = part[t];
    double p = (double)hist[t] * (1.0 / (double)NVEC);
    double vE = p * log(p + 1e-10);
    for (int off = 32; off; off >>= 1) {
        vL += __shfl_down(vL, off);
        vE += __shfl_down(vE, off);
    }
    __shared__ double lsL[16], lsE[16];
    int lane = t & 63, wv = t >> 6;
    if (lane == 0) { lsL[wv] = vL; lsE[wv] = vE; }
    __syncthreads();
    if (t == 0) {
        double SL = 0.0, SE = 0.0;
        for (int i = 0; i < 16; i++) { SL += lsL[i]; SE += lsE[i]; }
        double loss_cb = SL / (double)NELEM;     // == loss_commit numerically
        out[NELEM + NVEC]     = (float)(loss_cb + 0.25 * loss_cb);
        out[NELEM + NVEC + 1] = (float)exp(-SE);
    }
}

extern "C" void kernel_launch(void* const* d_in, const int* in_sizes, int n_in,
                              void* d_out, int out_size, void* d_ws, size_t ws_size,
                              hipStream_t stream) {
    const float* ze = (const float*)d_in[0];
    const float* cb = (const float*)d_in[1];
    float* out = (float*)d_out;
    char* ws = (char*)d_ws;

    int*    hist = (int*)(ws + WS_HIST);
    float*  n32  = (float*)(ws + WS_CBN32);
    double* part = (double*)(ws + WS_PART);
    __bf16* cbbf = (__bf16*)(ws + WS_CBBF);

    float* zq      = out;                 // (32, 64, 2048)
    float* codes_f = out + NELEM;         // (32, 2048) as float

    k_cbprep<<<16, 64, 0, stream>>>(cb, n32, cbbf, hist);   // also zeroes hist
    k_vq<<<NBLK, 256, 0, stream>>>(ze, cb, n32, cbbf, hist, codes_f, zq, part);
    k_final<<<1, 1024, 0, stream>>>(part, hist, out);
}

// Round 10
// 125.394 us; speedup vs baseline: 2.2144x; 1.0207x over previous
//
#include <hip/hip_runtime.h>
#include <math.h>

// Problem constants
#define NB 32
#define NC 64          // CODE_DIM
#define NK 2048
#define NCODES 1024
#define NVEC (NB*NK)          // 65536 vectors
#define NELEM (NB*NC*NK)      // 4194304 elements
#define NBLK (NVEC/64)        // 1024 blocks

#define MARGIN 1.5e-3f        // rigorous bf16-proxy bound (validated R5)
#define CAP 32

// ws layout (bytes)
#define WS_HIST  0            // int[1024]      = 4096
#define WS_CBN32 4096         // float[1024]    = 4096
#define WS_PART  8192         // double[1024]   = 8192
#define WS_CBBF  32768        // __bf16[65536]  = 131072

typedef __bf16 bf16x8 __attribute__((ext_vector_type(8)));
typedef float  f32x4  __attribute__((ext_vector_type(4)));
#define MFMA16(A, B, ACC) __builtin_amdgcn_mfma_f32_16x16x32_bf16(A, B, ACC, 0, 0, 0)

// --- codebook prep: numpy-exact fp32 norms (same summation order as validated
// version -> bit-identical n32) + bf16 copy; block 0 zeroes hist. ------------
__global__ void k_cbprep(const float* __restrict__ cb, float* __restrict__ n32,
                         __bf16* __restrict__ cbbf, int* __restrict__ hist) {
    const int t = threadIdx.x;
    const int j = blockIdx.x * 64 + t;   // 16 x 64 = 1024
    if (blockIdx.x == 0) {
        int4 z4; z4.x = 0; z4.y = 0; z4.z = 0; z4.w = 0;
#pragma unroll
        for (int i = 0; i < 4; i++) ((int4*)hist)[t * 4 + i] = z4;
    }
    const float* cr = cb + (size_t)j * NC;
    float x[64];
#pragma unroll
    for (int i = 0; i < 16; i++) {
        f32x4 tv = *(const f32x4*)(cr + 4 * i);
        x[4*i+0] = tv[0]; x[4*i+1] = tv[1]; x[4*i+2] = tv[2]; x[4*i+3] = tv[3];
    }
    // EXACT same chain as validated version (order preserved)
    float r[8];
#pragma unroll
    for (int q = 0; q < 8; q++) r[q] = __fmul_rn(x[q], x[q]);
#pragma unroll
    for (int i = 8; i < 64; i += 8)
#pragma unroll
        for (int q = 0; q < 8; q++)
            r[q] = __fadd_rn(r[q], __fmul_rn(x[i + q], x[i + q]));
    float s01 = __fadd_rn(r[0], r[1]), s23 = __fadd_rn(r[2], r[3]);
    float s45 = __fadd_rn(r[4], r[5]), s67 = __fadd_rn(r[6], r[7]);
    n32[j] = __fadd_rn(__fadd_rn(s01, s23), __fadd_rn(s45, s67));
    __bf16* br = cbbf + (size_t)j * NC;
#pragma unroll
    for (int i = 0; i < 8; i++) {
        bf16x8 o;
#pragma unroll
        for (int q = 0; q < 8; q++) o[q] = (__bf16)x[8*i + q];
        *(bf16x8*)(br + 8*i) = o;
    }
}

// --- fused VQ: single-MFMA-pass via (min1,min2,idx1) tracking ----------------
// Block: 256 thr = 4 waves; 64 vectors; grid 1024 (R2/R9 measured-best shape).
// NEW vs R9: pass 2 eliminated from the common path. Pass 1 tracks per lane
// per (vt,r): min1 (smallest pd), min2 (2nd smallest), idx1 (argmin code,
// first-wins on exact ties -> numpy rule preserved through exact rescore).
// After the global threshold gthr = gmin + MARGIN is known:
//   candidates = { idx1 | min1 <= gthr }   (distinct codes: lanes own columns)
// This set is complete UNLESS some lane has min2 <= gthr (>=2 near-ties in one
// lane) -- detected exactly per vector; only then a block-uniform fallback
// re-runs the old capture pass for the flagged vectors (~never taken at
// MARGIN=1.5e-3). Halves MFMA + codebook L2 streaming, drops one barrier.
// Cost: +48 VGPR -> ~90, FREE: occupancy is grid-limited (4 blk/CU for any
// VGPR<=128; launch_bounds(256,4) caps alloc at 128 so no R4-style spill).
// Banked lessons unchanged: R1/R3/R4/R5/R6/R8 (see session journal).
// Exact rescore chain and k_final untouched (bit-exact, validated).
// MFMA 16x16x32 bf16 layout (validated R5): A[m=lane&15][k=quad*8+j];
// B[n=lane&15][k=quad*8+j]; D col=lane&15 (code), row=quad*4+reg (vector).
__launch_bounds__(256, 4)
__global__ void k_vq(const float* __restrict__ ze, const float* __restrict__ cb,
                     const float* __restrict__ n32, const __bf16* __restrict__ cbbf,
                     int* __restrict__ hist, float* __restrict__ codes_f,
                     float* __restrict__ outq, double* __restrict__ part) {
    __shared__ float wmin[64][5];            // padded minor (bank spread)
    __shared__ float gthr[64];
    __shared__ int cnt[64];
    __shared__ int needv[64];
    __shared__ int blockneed;
    __shared__ int cand[64][CAP + 1];        // padded
    __shared__ unsigned long long keys2[64][5];  // padded
    __shared__ int codearr[64];
    __shared__ double lsd[4];

    const int t = threadIdx.x;
    const int L = t & 63;
    const int w = t >> 6;            // wave 0..3
    const int quad = L >> 4;
    const int col = L & 15;
    const int vec0 = blockIdx.x * 64;
    const int b = vec0 >> 11;
    const int k0 = vec0 & (NK - 1);
    const float* zbase = ze + (size_t)b * NC * NK + k0;

    // ---- A-frags for all 64 vectors (reg-resident, 32 VGPR) ----------------
    bf16x8 af[4][2];
#pragma unroll
    for (int vt = 0; vt < 4; vt++)
#pragma unroll
        for (int kt = 0; kt < 2; kt++)
#pragma unroll
            for (int j = 0; j < 8; j++)
                af[vt][kt][j] =
                    (__bf16)zbase[(size_t)(kt*32 + quad*8 + j) * NK + vt*16 + col];

    // ---- single pass: per-lane (min1, min2, idx1) over wave's 256 codes ----
    float m1[4][4], m2[4][4];
    int   i1[4][4];
#pragma unroll
    for (int vt = 0; vt < 4; vt++)
#pragma unroll
        for (int r = 0; r < 4; r++) {
            m1[vt][r] = 1e30f; m2[vt][r] = 1e30f; i1[vt][r] = 0;
        }
#pragma unroll 4
    for (int tile = 0; tile < 16; tile++) {   // unroll 4: limit B-load hoisting
        const __bf16* brow = cbbf + (size_t)(w*256 + tile*16 + col) * NC + quad*8;
        bf16x8 b0 = *(const bf16x8*)(brow);
        bf16x8 b1 = *(const bf16x8*)(brow + 32);
        float nvv = n32[w*256 + tile*16 + col];
        const int code = w*256 + tile*16 + col;
#pragma unroll
        for (int vt = 0; vt < 4; vt++) {   // 4 independent MFMA chains (ILP)
            f32x4 acc = {0.f, 0.f, 0.f, 0.f};
            acc = MFMA16(af[vt][0], b0, acc);
            acc = MFMA16(af[vt][1], b1, acc);
#pragma unroll
            for (int r = 0; r < 4; r++) {
                float pd = __fmaf_rn(-2.f, acc[r], nvv);  // == sub(nvv,mul(2,acc))
                bool lt = pd < m1[vt][r];                 // strict: first-wins ties
                float nm2 = fminf(m2[vt][r], pd);
                m2[vt][r] = lt ? m1[vt][r] : nm2;
                i1[vt][r] = lt ? code : i1[vt][r];
                m1[vt][r] = lt ? pd : m1[vt][r];
            }
        }
    }
    // one-time cross-col reduce of min1 (value only; idx resolved by rescore)
#pragma unroll
    for (int vt = 0; vt < 4; vt++)
#pragma unroll
        for (int r = 0; r < 4; r++) {
            float pm = m1[vt][r];
            pm = fminf(pm, __shfl_xor(pm, 1, 16));
            pm = fminf(pm, __shfl_xor(pm, 2, 16));
            pm = fminf(pm, __shfl_xor(pm, 4, 16));
            pm = fminf(pm, __shfl_xor(pm, 8, 16));
            if (col == 0) wmin[vt*16 + quad*4 + r][w] = pm;
        }
    __syncthreads();

    if (t < 64) {
        float g = wmin[t][0];
#pragma unroll
        for (int ww = 1; ww < 4; ww++) g = fminf(g, wmin[t][ww]);
        gthr[t] = g + MARGIN;
        cnt[t] = 0;
        needv[t] = 0;
    }
    if (t == 0) blockneed = 0;
    __syncthreads();

    // ---- candidate insertion from registers (no second codebook pass) ------
#pragma unroll
    for (int vt = 0; vt < 4; vt++)
#pragma unroll
        for (int r = 0; r < 4; r++) {
            const int m = vt*16 + quad*4 + r;
            const float thr = gthr[m];
            if (m1[vt][r] <= thr) {
                int slot = atomicAdd(&cnt[m], 1);
                if (slot < CAP) cand[m][slot] = i1[vt][r];
            }
            if (m2[vt][r] <= thr) { needv[m] = 1; blockneed = 1; }
        }
    __syncthreads();

    // ---- fallback capture pass (rare: >=2 near-ties within one lane) -------
    if (blockneed) {
        if (t < 64 && needv[t]) cnt[t] = 0;
        __syncthreads();
#pragma unroll 4
        for (int tile = 0; tile < 16; tile++) {
            const __bf16* brow = cbbf + (size_t)(w*256 + tile*16 + col) * NC + quad*8;
            bf16x8 b0 = *(const bf16x8*)(brow);
            bf16x8 b1 = *(const bf16x8*)(brow + 32);
            float nvv = n32[w*256 + tile*16 + col];
#pragma unroll
            for (int vt = 0; vt < 4; vt++) {
                f32x4 acc = {0.f, 0.f, 0.f, 0.f};
                acc = MFMA16(af[vt][0], b0, acc);
                acc = MFMA16(af[vt][1], b1, acc);
#pragma unroll
                for (int r = 0; r < 4; r++) {
                    const int m = vt*16 + quad*4 + r;
                    if (needv[m]) {
                        float pd = __fmaf_rn(-2.f, acc[r], nvv);
                        if (pd <= gthr[m]) {
                            int slot = atomicAdd(&cnt[m], 1);
                            if (slot < CAP) cand[m][slot] = w*256 + tile*16 + col;
                        }
                    }
                }
            }
        }
        __syncthreads();
    }

    // ---- exact rescore: 4 threads/vector, validated bit-exact fp32 chain ---
    {
        const int v = L;           // vector; this thread handles part w
        // t1 = np.sum(z*z), numpy-exact (redundant x4, bit-identical -- R2)
        float rr[8];
#pragma unroll
        for (int q = 0; q < 8; q++) {
            float xx = zbase[(size_t)q * NK + v];
            rr[q] = __fmul_rn(xx, xx);
        }
#pragma unroll
        for (int i = 8; i < 64; i += 8)
#pragma unroll
            for (int q = 0; q < 8; q++) {
                float xx = zbase[(size_t)(i + q) * NK + v];
                rr[q] = __fadd_rn(rr[q], __fmul_rn(xx, xx));
            }
        float s01 = __fadd_rn(rr[0], rr[1]), s23 = __fadd_rn(rr[2], rr[3]);
        float s45 = __fadd_rn(rr[4], rr[5]), s67 = __fadd_rn(rr[6], rr[7]);
        float t1 = __fadd_rn(__fadd_rn(s01, s23), __fadd_rn(s45, s67));

        int cc = cnt[v];
        unsigned long long kmin = 0xFFFFFFFFFFFFFFFFULL;
        if (cc <= CAP) {
            for (int si = w; si < cc; si += 4) {
                int j = cand[v][si];
                const float* cr = cb + (size_t)j * NC;
                float a = 0.f;
#pragma unroll
                for (int c = 0; c < NC; c++)
                    a = __fmaf_rn(zbase[(size_t)c * NK + v], cr[c], a);
                float d = __fmaf_rn(-2.f, a, __fadd_rn(t1, n32[j]));
                unsigned long long key =
                    ((unsigned long long)__float_as_uint(d) << 32) | (unsigned int)j;
                if (key < kmin) kmin = key;
            }
        } else {   // overflow fallback: exact full scan split over 4 threads
            for (int j = w * 256; j < (w + 1) * 256; j++) {
                const float* cr = cb + (size_t)j * NC;
                float a = 0.f;
#pragma unroll
                for (int c = 0; c < NC; c++)
                    a = __fmaf_rn(zbase[(size_t)c * NK + v], cr[c], a);
                float d = __fmaf_rn(-2.f, a, __fadd_rn(t1, n32[j]));
                unsigned long long key =
                    ((unsigned long long)__float_as_uint(d) << 32) | (unsigned int)j;
                if (key < kmin) kmin = key;
            }
        }
        keys2[v][w] = kmin;
    }
    __syncthreads();

    if (t < 64) {   // merge 4 partial keys: min dist, ties -> min idx (np rule)
        unsigned long long kmin = keys2[t][0];
#pragma unroll
        for (int ww = 1; ww < 4; ww++) {
            unsigned long long kk = keys2[t][ww];
            if (kk < kmin) kmin = kk;
        }
        int code = (int)(kmin & 0xFFFFFFFFu);
        codearr[t] = code;
        codes_f[vec0 + t] = (float)code;
        atomicAdd(&hist[code], 1);
    }
    __syncthreads();

    // ---- quant epilogue: float4; per c-row 16 thr x 16B = 256B contiguous --
    double s = 0.0;
    float* ob = outq + (size_t)b * NC * NK + k0;
    const int c0 = t >> 4;             // 0..15
    const int v0 = (t & 15) * 4;       // 0,4,..,60
    int cds[4];
#pragma unroll
    for (int u = 0; u < 4; u++) cds[u] = codearr[v0 + u];
#pragma unroll
    for (int half = 0; half < 4; half++) {
        const int c = c0 + half * 16;
        f32x4 zv = *(const f32x4*)(zbase + (size_t)c * NK + v0);
        f32x4 ov;
#pragma unroll
        for (int u = 0; u < 4; u++) {
            float qv = cb[(size_t)cds[u] * NC + c];
            ov[u] = __fadd_rn(zv[u], __fsub_rn(qv, zv[u]));
            double d = (double)qv - (double)zv[u];
            s += d * d;
        }
        *(f32x4*)(ob + (size_t)c * NK + v0) = ov;
    }
    for (int off = 32; off; off >>= 1) s += __shfl_down(s, off);
    if (L == 0) lsd[w] = s;
    __syncthreads();
    if (t == 0) part[blockIdx.x] = lsd[0] + lsd[1] + lsd[2] + lsd[3];
}

// --- final scalars: loss_vq and perplexity (separate dispatch: R8 lesson) ---
__launch_bounds__(1024)
__global__ void k_final(const double* __restrict__ part, const int* __restrict__ hist,
                        float* __restrict__ out) {
    int t = threadIdx.x;                         // 1024 threads = NBLK partials
    double vL = part[t];
    double p = (double)hist[t] * (1.0 / (double)NVEC);
    double vE = p * log(p + 1e-10);
    for (int off = 32; off; off >>= 1) {
        vL += __shfl_down(vL, off);
        vE += __shfl_down(vE, off);
    }
    __shared__ double lsL[16], lsE[16];
    int lane = t & 63, wv = t >> 6;
    if (lane == 0) { lsL[wv] = vL; lsE[wv] = vE; }
    __syncthreads();
    if (t == 0) {
        double SL = 0.0, SE = 0.0;
        for (int i = 0; i < 16; i++) { SL += lsL[i]; SE += lsE[i]; }
        double loss_cb = SL / (double)NELEM;     // == loss_commit numerically
        out[NELEM + NVEC]     = (float)(loss_cb + 0.25 * loss_cb);
        out[NELEM + NVEC + 1] = (float)exp(-SE);
    }
}

extern "C" void kernel_launch(void* const* d_in, const int* in_sizes, int n_in,
                              void* d_out, int out_size, void* d_ws, size_t ws_size,
                              hipStream_t stream) {
    const float* ze = (const float*)d_in[0];
    const float* cb = (const float*)d_in[1];
    float* out = (float*)d_out;
    char* ws = (char*)d_ws;

    int*    hist = (int*)(ws + WS_HIST);
    float*  n32  = (float*)(ws + WS_CBN32);
    double* part = (double*)(ws + WS_PART);
    __bf16* cbbf = (__bf16*)(ws + WS_CBBF);

    float* zq      = out;                 // (32, 64, 2048)
    float* codes_f = out + NELEM;         // (32, 2048) as float

    k_cbprep<<<16, 64, 0, stream>>>(cb, n32, cbbf, hist);   // also zeroes hist
    k_vq<<<NBLK, 256, 0, stream>>>(ze, cb, n32, cbbf, hist, codes_f, zq, part);
    k_final<<<1, 1024, 0, stream>>>(part, hist, out);
}